// Round 7
// baseline (312.020 us; speedup 1.0000x reference)
//
#include <hip/hip_runtime.h>
#include <hip/hip_bf16.h>

#define BB 2
#define NN 8192
#define SPL 16
#define CAND (NN/SPL)
#define NPTS (BB*NN)

// ---- workspace layout (units: 4-byte words) ----
#define POS4_OFF 0u
#define WBUF_OFF 65536u
#define XB_OFF   (WBUF_OFF + 33792u)
#define PART_OFF XB_OFF        /* PART (16.7MB, [256][NPTS]) dead after k2 */
#define QB_OFF   (XB_OFF + 1048576u)
#define KB_OFF   (QB_OFF + 1048576u)
#define VB_OFF   (KB_OFF + 1048576u)
#define IDX_OFF  (VB_OFF + 1048576u)
#define WT_OFF   (IDX_OFF + 262144u)   /* 4 mats x 4096 bf16 = 8192 words */

// ---- wbuf internal offsets (words) ----
#define W_EMB 0
#define W_Q   4096
#define W_K   8192
#define W_V   12288
#define W_PE2 16384
#define W_AT1 20480
#define W_AT2 24576
#define W_OUT 28672
#define W_PE1 32768
#define B_EMB 32960
#define B_PE1 33024
#define B_PE2 33088
#define B_AT1 33152
#define B_AT2 33216
#define B_OUT 33280

typedef __attribute__((ext_vector_type(8))) short bf16x8;
typedef __attribute__((ext_vector_type(4))) float f32x4;

__device__ __forceinline__ unsigned umn(unsigned a, unsigned b) {
#if __has_builtin(__builtin_elementwise_min)
  return __builtin_elementwise_min(a, b);
#else
  return a < b ? a : b;
#endif
}
__device__ __forceinline__ unsigned umx(unsigned a, unsigned b) {
#if __has_builtin(__builtin_elementwise_max)
  return __builtin_elementwise_max(a, b);
#else
  return a < b ? b : a;
#endif
}

__device__ inline unsigned short f2bf(float x) {
  __hip_bfloat16 b = __float2bfloat16(x);
  return *(unsigned short*)&b;
}

// column-block rotate swizzle for conflict-free ds_read_b128 fragments
#define HCOL(c, j) ((((((c) >> 3) + (j)) & 7) << 3) | ((c) & 7))

// ============================ K0: stage pos4(+|c|^2), weights, bf16-T mats ====
__global__ __launch_bounds__(256) void k0_stage(
    const float* __restrict__ pos,
    const float* __restrict__ emb_w, const float* __restrict__ emb_b,
    const float* __restrict__ wq, const float* __restrict__ wk,
    const float* __restrict__ wv,
    const float* __restrict__ pe_w1, const float* __restrict__ pe_b1,
    const float* __restrict__ pe_w2, const float* __restrict__ pe_b2,
    const float* __restrict__ at_w1, const float* __restrict__ at_b1,
    const float* __restrict__ at_w2, const float* __restrict__ at_b2,
    const float* __restrict__ out_w, const float* __restrict__ out_b,
    float* __restrict__ ws)
{
  int t = blockIdx.x * 256 + threadIdx.x;
  if (t < NPTS) {
    float x = pos[t * 3 + 0], y = pos[t * 3 + 1], z = pos[t * 3 + 2];
    float* o = ws + POS4_OFF + t * 4;
    o[0] = x; o[1] = y; o[2] = z;
    o[3] = fmaf(x, x, fmaf(y, y, z * z));
    return;
  }
  t -= NPTS;
  float* wbuf = ws + WBUF_OFF;
  if (t < 32768) {
    const float* s;
    switch (t >> 12) {
      case 0: s = emb_w; break;
      case 1: s = wq;    break;
      case 2: s = wk;    break;
      case 3: s = wv;    break;
      case 4: s = pe_w2; break;
      case 5: s = at_w1; break;
      case 6: s = at_w2; break;
      default: s = out_w; break;
    }
    wbuf[t] = s[t & 4095];
    return;
  }
  t -= 32768;
  if (t < 192) { wbuf[W_PE1 + t] = pe_w1[t]; return; }
  t -= 192;
  if (t < 384) {
    const float* s;
    switch (t >> 6) {
      case 0: s = emb_b; break;
      case 1: s = pe_b1; break;
      case 2: s = pe_b2; break;
      case 3: s = at_b1; break;
      case 4: s = at_b2; break;
      default: s = out_b; break;
    }
    wbuf[B_EMB + t] = s[t & 63];
    return;
  }
  t -= 384;
  if (t < 16384) {  // bf16 transposed mats: wt[m][f*64+c] = W_m[c*64+f]
    unsigned short* wt = (unsigned short*)(ws + WT_OFF);
    const float* s;
    switch (t >> 12) {
      case 0: s = pe_w2; break;
      case 1: s = at_w1; break;
      case 2: s = at_w2; break;
      default: s = out_w; break;
    }
    int idx = t & 4095, f = idx >> 6, c = idx & 63;
    wt[t] = f2bf(s[c * 64 + f]);
  }
}

// ============================ K1: KNN, batch-16 OEMS selection ================
__global__ __launch_bounds__(256) void k1_knn(const float* __restrict__ pos4,
                                              unsigned* __restrict__ part)
{
  const int tid = threadIdx.x;
  const int g = blockIdx.x * 256 + tid;
  const int s = blockIdx.y;
  const int bu = __builtin_amdgcn_readfirstlane(g >> 13);
  const float4* __restrict__ allp = (const float4*)pos4;
  const float4 q = allp[g];
  const float qx2 = -2.f * q.x, qy2 = -2.f * q.y, qz2 = -2.f * q.z;
  const float sqq = q.w + 1e-5f;     // bias keeps d2>0 under rounding: no fmax
  const float4* __restrict__ cand = allp + (bu * NN + s * CAND);
  unsigned m[16];
#pragma unroll
  for (int i = 0; i < 16; i++) m[i] = 0xFFFFFFFFu;
  const unsigned jb = (unsigned)(s * CAND);

  constexpr int OE[63][2] = {
    {0,1},{2,3},{4,5},{6,7},{8,9},{10,11},{12,13},{14,15},
    {0,2},{1,3},{4,6},{5,7},{8,10},{9,11},{12,14},{13,15},
    {1,2},{5,6},{9,10},{13,14},
    {0,4},{1,5},{2,6},{3,7},{8,12},{9,13},{10,14},{11,15},
    {2,4},{3,5},{10,12},{11,13},
    {1,2},{3,4},{5,6},{9,10},{11,12},{13,14},
    {0,8},{1,9},{2,10},{3,11},{4,12},{5,13},{6,14},{7,15},
    {4,8},{5,9},{6,10},{7,11},
    {2,4},{3,5},{6,8},{7,9},{10,12},{11,13},
    {1,2},{3,4},{5,6},{7,8},{9,10},{11,12},{13,14}
  };

  for (int j0 = 0; j0 < CAND; j0 += 16) {
    unsigned b[16];
#pragma unroll
    for (int i = 0; i < 16; i++) {
      float4 cp = cand[j0 + i];                // wave-uniform -> scalar loads
      float d2 = fmaf(cp.x, qx2, fmaf(cp.y, qy2, fmaf(cp.z, qz2, cp.w + sqq)));
      b[i] = (__float_as_uint(d2) & 0xFFFFE000u) | (jb + (unsigned)(j0 + i));
    }
#pragma unroll
    for (int c = 0; c < 63; c++) {
      const int x = OE[c][0], y = OE[c][1];
      unsigned lo = umn(b[x], b[y]);
      unsigned hi = umx(b[x], b[y]);
      b[x] = hi; b[y] = lo;
    }
#pragma unroll
    for (int i = 0; i < 16; i++) m[i] = umn(m[i], b[i]);
#pragma unroll
    for (int d = 8; d; d >>= 1) {
#pragma unroll
      for (int i = 0; i < 16; i++) {
        if ((i & d) == 0) {
          const int l = i | d;
          unsigned lo = umn(m[i], m[l]);
          unsigned hi = umx(m[i], m[l]);
          m[i] = lo; m[l] = hi;
        }
      }
    }
  }
#pragma unroll
  for (int i = 0; i < 16; i++)
    part[(unsigned)(s * 16 + i) * NPTS + (unsigned)g] = m[i];
}

// ============================ K2: merge 16 sorted 16-lists (coalesced) ========
__global__ __launch_bounds__(256) void k2_merge(const unsigned* __restrict__ part,
                                                int* __restrict__ knn_idx)
{
  const int g = blockIdx.x * 256 + threadIdx.x;
  unsigned run[16];
#pragma unroll
  for (int i = 0; i < 16; i++) run[i] = part[i * NPTS + g];
#pragma unroll
  for (int l = 1; l < SPL; l++) {
#pragma unroll
    for (int i = 0; i < 16; i++)
      run[i] = umn(run[i], part[(l * 16 + 15 - i) * NPTS + g]);
#pragma unroll
    for (int d = 8; d; d >>= 1) {
#pragma unroll
      for (int i = 0; i < 16; i++) {
        if ((i & d) == 0) {
          const int l2 = i | d;
          unsigned lo = umn(run[i], run[l2]);
          unsigned hi = umx(run[i], run[l2]);
          run[i] = lo; run[l2] = hi;
        }
      }
    }
  }
  const int base = (g >> 13) * NN;
  int outv[16];
#pragma unroll
  for (int i = 0; i < 16; i++) outv[i] = base + (int)(run[i] & 0x1FFFu);
  int4* o = (int4*)(knn_idx + g * 16);
  o[0] = make_int4(outv[0], outv[1], outv[2], outv[3]);
  o[1] = make_int4(outv[4], outv[5], outv[6], outv[7]);
  o[2] = make_int4(outv[8], outv[9], outv[10], outv[11]);
  o[3] = make_int4(outv[12], outv[13], outv[14], outv[15]);
}

// ============================ K34: fused x=feat@emb+b ; q,k,v = x@{wq,wk,wv} ==
__global__ __launch_bounds__(256) void k34_embqkv(
    const float* __restrict__ feat, const float* __restrict__ wb,
    float* __restrict__ qo, float* __restrict__ ko, float* __restrict__ vo)
{
  __shared__ float wl[16384];   // emb | q | k | v  (64 KB)
  __shared__ float xl[2048];    // 32 rows x 64     (8 KB)
  for (int i = threadIdx.x; i < 16384; i += 256) wl[i] = wb[W_EMB + i];
  const int col = threadIdx.x & 63;
  const int rg = threadIdx.x >> 6;
  const int row0 = blockIdx.x * 32 + rg * 8;
  const int rowu = __builtin_amdgcn_readfirstlane(row0);
  __syncthreads();
  // stage A: x rows -> LDS
  {
    float acc[8];
    float bias = wb[B_EMB + col];
#pragma unroll
    for (int r = 0; r < 8; r++) acc[r] = bias;
    for (int c = 0; c < 64; c++) {
      float w = wl[c * 64 + col];
      const float* fp = feat + rowu * 64 + c;   // uniform -> scalar loads
#pragma unroll
      for (int r = 0; r < 8; r++) acc[r] = fmaf(fp[r * 64], w, acc[r]);
    }
#pragma unroll
    for (int r = 0; r < 8; r++) xl[(rg * 8 + r) * 64 + col] = acc[r];
  }
  __syncthreads();
  // stage B: qkv from LDS x (xv reads are same-address broadcasts)
  float aq[8], ak[8], av[8];
#pragma unroll
  for (int r = 0; r < 8; r++) { aq[r] = 0.f; ak[r] = 0.f; av[r] = 0.f; }
  for (int c = 0; c < 64; c++) {
    float w0 = wl[4096 + c * 64 + col];
    float w1 = wl[8192 + c * 64 + col];
    float w2 = wl[12288 + c * 64 + col];
#pragma unroll
    for (int r = 0; r < 8; r++) {
      float xv = xl[(rg * 8 + r) * 64 + c];
      aq[r] = fmaf(xv, w0, aq[r]);
      ak[r] = fmaf(xv, w1, ak[r]);
      av[r] = fmaf(xv, w2, av[r]);
    }
  }
#pragma unroll
  for (int r = 0; r < 8; r++) {
    qo[(row0 + r) * 64 + col] = aq[r];
    ko[(row0 + r) * 64 + col] = ak[r];
    vo[(row0 + r) * 64 + col] = av[r];
  }
}

// ============================ K5: MFMA fused posenc/attn/softmax/out ==========
// B-fragments for the 3 inner matrices live in block LDS (swizzled) -> frees
// ~96 VGPRs; __launch_bounds__(256,4) pins 4 waves/SIMD. LDS: 8+2+24=34 KB.
__device__ inline void mv(const unsigned short* hm, const unsigned short* wm,
                          const float bias[4], int ln, int quad, f32x4 acc[4])
{
  bf16x8 a0 = *(const bf16x8*)(hm + ln * 64 + (((0 + quad + ln) & 7) << 3));
  bf16x8 a1 = *(const bf16x8*)(hm + ln * 64 + (((4 + quad + ln) & 7) << 3));
#pragma unroll
  for (int t = 0; t < 4; t++) {
    const int f = t * 16 + ln;
    bf16x8 b0 = *(const bf16x8*)(wm + f * 64 + (((0 + quad + ln) & 7) << 3));
    bf16x8 b1 = *(const bf16x8*)(wm + f * 64 + (((4 + quad + ln) & 7) << 3));
    f32x4 a = {bias[t], bias[t], bias[t], bias[t]};
    a = __builtin_amdgcn_mfma_f32_16x16x32_bf16(a0, b0, a, 0, 0, 0);
    a = __builtin_amdgcn_mfma_f32_16x16x32_bf16(a1, b1, a, 0, 0, 0);
    acc[t] = a;
  }
}

__global__ __launch_bounds__(256, 4) void k5_attn(
    const float* __restrict__ pos4, const float* __restrict__ qg,
    const float* __restrict__ kg, const float* __restrict__ vg,
    const float* __restrict__ featf, const float* __restrict__ wb,
    const unsigned short* __restrict__ wt, const int* __restrict__ knn,
    float* __restrict__ out)
{
  __shared__ unsigned short hma[4][1024];   // per-wave 16x64 bf16 h (8 KB)
  __shared__ unsigned short resm[1024];     // 16 points x 64 bf16   (2 KB)
  __shared__ unsigned short wtl[3 * 4096];  // pe_w2|at_w1|at_w2 swz (24 KB)
  const int tid = threadIdx.x;
  const int wid = tid >> 6, lane = tid & 63;
  const int ln = lane & 15, quad = lane >> 4;
  unsigned short* hm = hma[wid];

  // cooperative swizzled copy of the 3 inner B-matrices into LDS
  for (int i = tid; i < 3 * 4096; i += 256) {
    const int f = (i >> 6) & 63, c = i & 63;
    wtl[(i & ~63) + HCOL(c, f)] = wt[i];
  }
  // epilogue fragments stay in regs (8 VGPRs)
  bf16x8 bo[2];
#pragma unroll
  for (int ks = 0; ks < 2; ks++)
    bo[ks] = *(const bf16x8*)(wt + 3 * 4096 + (wid * 16 + ln) * 64 +
                              ks * 32 + quad * 8);

  float pw10 = wb[W_PE1 + lane], pw11 = wb[W_PE1 + 64 + lane],
        pw12 = wb[W_PE1 + 128 + lane];
  float pb1 = wb[B_PE1 + lane];
  float bpe[4], ba1[4], ba2[4];
#pragma unroll
  for (int t = 0; t < 4; t++) {
    bpe[t] = wb[B_PE2 + t * 16 + ln];
    ba1[t] = wb[B_AT1 + t * 16 + ln];
    ba2[t] = wb[B_AT2 + t * 16 + ln];
  }
  __syncthreads();

  for (int pp = 0; pp < 4; pp++) {
    const int p = blockIdx.x * 16 + wid * 4 + pp;
    const int ps = __builtin_amdgcn_readfirstlane(p);
    const int4* ip4 = (const int4*)(knn + ps * 16);
    int jj[16];
#pragma unroll
    for (int u = 0; u < 4; u++) {
      int4 t4 = ip4[u];
      jj[u*4+0] = t4.x; jj[u*4+1] = t4.y; jj[u*4+2] = t4.z; jj[u*4+3] = t4.w;
    }
    const float* mp = pos4 + ps * 4;
    float pnx = mp[0], pny = mp[1], pnz = mp[2];
#pragma unroll
    for (int j = 0; j < 16; j++) {
      const float* np_ = pos4 + jj[j] * 4;
      float h1 = fmaf(np_[2] - pnz, pw12,
                 fmaf(np_[1] - pny, pw11,
                 fmaf(np_[0] - pnx, pw10, pb1)));
      hm[j * 64 + HCOL(lane, j)] = f2bf(fmaxf(h1, 0.f));
    }
    f32x4 accp[4];
    mv(hm, wtl, bpe, ln, quad, accp);          // posenc
    float vpe[4][4], qv[4];
#pragma unroll
    for (int t = 0; t < 4; t++) qv[t] = qg[p * 64 + t * 16 + ln];
#pragma unroll
    for (int t = 0; t < 4; t++) {
      const int ft = t * 16 + ln;
#pragma unroll
      for (int r = 0; r < 4; r++) {
        const int j = quad * 4 + r;
        float pe = accp[t][r];
        float kf = kg[jj[j] * 64 + ft];
        float vf = vg[jj[j] * 64 + ft];
        vpe[t][r] = vf + pe;
        hm[j * 64 + HCOL(ft, j)] = f2bf(qv[t] - kf + pe);
      }
    }
    f32x4 acch[4];
    mv(hm, wtl + 4096, ba1, ln, quad, acch);   // hh @ at_w1 + b
#pragma unroll
    for (int t = 0; t < 4; t++)
#pragma unroll
      for (int r = 0; r < 4; r++) {
        const int j = quad * 4 + r;
        hm[j * 64 + HCOL(t * 16 + ln, j)] = f2bf(fmaxf(acch[t][r], 0.f));
      }
    f32x4 lg[4];
    mv(hm, wtl + 8192, ba2, ln, quad, lg);     // logits
    const int pb = wid * 4 + pp;
#pragma unroll
    for (int t = 0; t < 4; t++) {
      float mx = fmaxf(fmaxf(lg[t][0], lg[t][1]), fmaxf(lg[t][2], lg[t][3]));
      mx = fmaxf(mx, __shfl_xor(mx, 16));
      mx = fmaxf(mx, __shfl_xor(mx, 32));
      float e0 = __expf((lg[t][0] - mx) * 0.125f);
      float e1 = __expf((lg[t][1] - mx) * 0.125f);
      float e2 = __expf((lg[t][2] - mx) * 0.125f);
      float e3 = __expf((lg[t][3] - mx) * 0.125f);
      float ss = (e0 + e1) + (e2 + e3);
      float dt = fmaf(e3, vpe[t][3], fmaf(e2, vpe[t][2],
                 fmaf(e1, vpe[t][1], e0 * vpe[t][0])));
      ss += __shfl_xor(ss, 16); ss += __shfl_xor(ss, 32);
      dt += __shfl_xor(dt, 16); dt += __shfl_xor(dt, 32);
      float res = dt / ss;
      if (quad == 0) resm[pb * 64 + HCOL(t * 16 + ln, pb)] = f2bf(res);
    }
  }
  __syncthreads();
  // epilogue: 16 points = 1 M-tile x 4 N-tiles; wave wid handles N-tile wid
  {
    const int nt = wid;
    float ob = wb[B_OUT + nt * 16 + ln];
    f32x4 acc = {ob, ob, ob, ob};
#pragma unroll
    for (int ks = 0; ks < 2; ks++) {
      bf16x8 a = *(const bf16x8*)(resm + ln * 64 +
                                  (((ks * 4 + quad + ln) & 7) << 3));
      acc = __builtin_amdgcn_mfma_f32_16x16x32_bf16(a, bo[ks], acc, 0, 0, 0);
    }
#pragma unroll
    for (int r = 0; r < 4; r++) {
      const int pt = blockIdx.x * 16 + quad * 4 + r;
      const int f = nt * 16 + ln;
      out[pt * 64 + f] = acc[r] + featf[pt * 64 + f];
    }
  }
}

// ============================ launcher ========================================
extern "C" void kernel_launch(void* const* d_in, const int* in_sizes, int n_in,
                              void* d_out, int out_size, void* d_ws, size_t ws_size,
                              hipStream_t stream)
{
  (void)in_sizes; (void)n_in; (void)out_size; (void)ws_size;
  const float* pos   = (const float*)d_in[0];
  const float* feat  = (const float*)d_in[1];
  const float* emb_w = (const float*)d_in[2];
  const float* emb_b = (const float*)d_in[3];
  const float* wq    = (const float*)d_in[4];
  const float* wk    = (const float*)d_in[5];
  const float* wv    = (const float*)d_in[6];
  const float* pe_w1 = (const float*)d_in[7];
  const float* pe_b1 = (const float*)d_in[8];
  const float* pe_w2 = (const float*)d_in[9];
  const float* pe_b2 = (const float*)d_in[10];
  const float* at_w1 = (const float*)d_in[11];
  const float* at_b1 = (const float*)d_in[12];
  const float* at_w2 = (const float*)d_in[13];
  const float* at_b2 = (const float*)d_in[14];
  const float* out_w = (const float*)d_in[15];
  const float* out_b = (const float*)d_in[16];
  float* ws = (float*)d_ws;

  k0_stage<<<259, 256, 0, stream>>>(pos, emb_w, emb_b, wq, wk, wv,
      pe_w1, pe_b1, pe_w2, pe_b2, at_w1, at_b1, at_w2, at_b2, out_w, out_b, ws);
  dim3 g1(NPTS / 256, SPL);
  k1_knn<<<g1, 256, 0, stream>>>(ws + POS4_OFF, (unsigned*)ws + PART_OFF);
  k2_merge<<<NPTS / 256, 256, 0, stream>>>((unsigned*)ws + PART_OFF,
                                           (int*)ws + IDX_OFF);
  k34_embqkv<<<NPTS / 32, 256, 0, stream>>>(feat, ws + WBUF_OFF,
                                            ws + QB_OFF, ws + KB_OFF, ws + VB_OFF);
  k5_attn<<<NPTS / 16, 256, 0, stream>>>(ws + POS4_OFF, ws + QB_OFF, ws + KB_OFF,
      ws + VB_OFF, feat, ws + WBUF_OFF, (unsigned short*)(ws + WT_OFF),
      (int*)ws + IDX_OFF, (float*)d_out);
}

// Round 8
// 268.793 us; speedup vs baseline: 1.1608x; 1.1608x over previous
//
#include <hip/hip_runtime.h>
#include <hip/hip_bf16.h>

#define BB 2
#define NN 8192
#define SPL 16
#define CAND (NN/SPL)
#define NPTS (BB*NN)

// ---- workspace layout (units: 4-byte words) ----
#define POS4_OFF 0u
#define WBUF_OFF 65536u
#define PART_OFF 99328u                 /* 256*NPTS = 4,194,304 words; dead after k2 */
#define QB_OFF   99328u                 /* overlays PART (born at k34, after k2) */
#define KVB_OFF  (QB_OFF + 1048576u)    /* kv interleaved [p][128]: 2,097,152 words */
#define IDX_OFF  4293632u               /* after PART */
#define WT_OFF   (IDX_OFF + 262144u)    /* 4 mats x 4096 bf16 = 8192 words */

// ---- wbuf internal offsets (words) ----
#define W_EMB 0
#define W_Q   4096
#define W_K   8192
#define W_V   12288
#define W_PE2 16384
#define W_AT1 20480
#define W_AT2 24576
#define W_OUT 28672
#define W_PE1 32768
#define B_EMB 32960
#define B_PE1 33024
#define B_PE2 33088
#define B_AT1 33152
#define B_AT2 33216
#define B_OUT 33280

typedef __attribute__((ext_vector_type(8))) short bf16x8;
typedef __attribute__((ext_vector_type(4))) float f32x4;

__device__ __forceinline__ unsigned umn(unsigned a, unsigned b) {
#if __has_builtin(__builtin_elementwise_min)
  return __builtin_elementwise_min(a, b);
#else
  return a < b ? a : b;
#endif
}
__device__ __forceinline__ unsigned umx(unsigned a, unsigned b) {
#if __has_builtin(__builtin_elementwise_max)
  return __builtin_elementwise_max(a, b);
#else
  return a < b ? b : a;
#endif
}

__device__ inline unsigned short f2bf(float x) {
  __hip_bfloat16 b = __float2bfloat16(x);
  return *(unsigned short*)&b;
}

// column-block rotate swizzle for conflict-free ds_read_b128 fragments
#define HCOL(c, j) ((((((c) >> 3) + (j)) & 7) << 3) | ((c) & 7))

// ============================ K0: stage pos4(+|c|^2), weights, bf16-T mats ====
__global__ __launch_bounds__(256) void k0_stage(
    const float* __restrict__ pos,
    const float* __restrict__ emb_w, const float* __restrict__ emb_b,
    const float* __restrict__ wq, const float* __restrict__ wk,
    const float* __restrict__ wv,
    const float* __restrict__ pe_w1, const float* __restrict__ pe_b1,
    const float* __restrict__ pe_w2, const float* __restrict__ pe_b2,
    const float* __restrict__ at_w1, const float* __restrict__ at_b1,
    const float* __restrict__ at_w2, const float* __restrict__ at_b2,
    const float* __restrict__ out_w, const float* __restrict__ out_b,
    float* __restrict__ ws)
{
  int t = blockIdx.x * 256 + threadIdx.x;
  if (t < NPTS) {
    float x = pos[t * 3 + 0], y = pos[t * 3 + 1], z = pos[t * 3 + 2];
    float* o = ws + POS4_OFF + t * 4;
    o[0] = x; o[1] = y; o[2] = z;
    o[3] = fmaf(x, x, fmaf(y, y, z * z));
    return;
  }
  t -= NPTS;
  float* wbuf = ws + WBUF_OFF;
  if (t < 32768) {
    const float* s;
    switch (t >> 12) {
      case 0: s = emb_w; break;
      case 1: s = wq;    break;
      case 2: s = wk;    break;
      case 3: s = wv;    break;
      case 4: s = pe_w2; break;
      case 5: s = at_w1; break;
      case 6: s = at_w2; break;
      default: s = out_w; break;
    }
    wbuf[t] = s[t & 4095];
    return;
  }
  t -= 32768;
  if (t < 192) { wbuf[W_PE1 + t] = pe_w1[t]; return; }
  t -= 192;
  if (t < 384) {
    const float* s;
    switch (t >> 6) {
      case 0: s = emb_b; break;
      case 1: s = pe_b1; break;
      case 2: s = pe_b2; break;
      case 3: s = at_b1; break;
      case 4: s = at_b2; break;
      default: s = out_b; break;
    }
    wbuf[B_EMB + t] = s[t & 63];
    return;
  }
  t -= 384;
  if (t < 16384) {  // bf16 transposed mats; mats 0-2 PRE-SWIZZLED for LDS reads
    unsigned short* wt = (unsigned short*)(ws + WT_OFF);
    const float* s;
    const int m = t >> 12;
    switch (m) {
      case 0: s = pe_w2; break;
      case 1: s = at_w1; break;
      case 2: s = at_w2; break;
      default: s = out_w; break;
    }
    int idx = t & 4095, f = idx >> 6, c = idx & 63;
    const int col = (m < 3) ? HCOL(c, f) : c;
    wt[m * 4096 + f * 64 + col] = f2bf(s[c * 64 + f]);
  }
}

// ============================ K1: KNN, batch-16 OEMS selection ================
__global__ __launch_bounds__(256) void k1_knn(const float* __restrict__ pos4,
                                              unsigned* __restrict__ part)
{
  const int tid = threadIdx.x;
  const int g = blockIdx.x * 256 + tid;
  const int s = blockIdx.y;
  const int bu = __builtin_amdgcn_readfirstlane(g >> 13);
  const float4* __restrict__ allp = (const float4*)pos4;
  const float4 q = allp[g];
  const float qx2 = -2.f * q.x, qy2 = -2.f * q.y, qz2 = -2.f * q.z;
  const float sqq = q.w + 1e-5f;     // bias keeps d2>0 under rounding: no fmax
  const float4* __restrict__ cand = allp + (bu * NN + s * CAND);
  unsigned m[16];
#pragma unroll
  for (int i = 0; i < 16; i++) m[i] = 0xFFFFFFFFu;
  const unsigned jb = (unsigned)(s * CAND);

  constexpr int OE[63][2] = {
    {0,1},{2,3},{4,5},{6,7},{8,9},{10,11},{12,13},{14,15},
    {0,2},{1,3},{4,6},{5,7},{8,10},{9,11},{12,14},{13,15},
    {1,2},{5,6},{9,10},{13,14},
    {0,4},{1,5},{2,6},{3,7},{8,12},{9,13},{10,14},{11,15},
    {2,4},{3,5},{10,12},{11,13},
    {1,2},{3,4},{5,6},{9,10},{11,12},{13,14},
    {0,8},{1,9},{2,10},{3,11},{4,12},{5,13},{6,14},{7,15},
    {4,8},{5,9},{6,10},{7,11},
    {2,4},{3,5},{6,8},{7,9},{10,12},{11,13},
    {1,2},{3,4},{5,6},{7,8},{9,10},{11,12},{13,14}
  };

  for (int j0 = 0; j0 < CAND; j0 += 16) {
    unsigned b[16];
#pragma unroll
    for (int i = 0; i < 16; i++) {
      float4 cp = cand[j0 + i];                // wave-uniform -> scalar loads
      float d2 = fmaf(cp.x, qx2, fmaf(cp.y, qy2, fmaf(cp.z, qz2, cp.w + sqq)));
      b[i] = (__float_as_uint(d2) & 0xFFFFE000u) | (jb + (unsigned)(j0 + i));
    }
#pragma unroll
    for (int c = 0; c < 63; c++) {
      const int x = OE[c][0], y = OE[c][1];
      unsigned lo = umn(b[x], b[y]);
      unsigned hi = umx(b[x], b[y]);
      b[x] = hi; b[y] = lo;
    }
#pragma unroll
    for (int i = 0; i < 16; i++) m[i] = umn(m[i], b[i]);
#pragma unroll
    for (int d = 8; d; d >>= 1) {
#pragma unroll
      for (int i = 0; i < 16; i++) {
        if ((i & d) == 0) {
          const int l = i | d;
          unsigned lo = umn(m[i], m[l]);
          unsigned hi = umx(m[i], m[l]);
          m[i] = lo; m[l] = hi;
        }
      }
    }
  }
#pragma unroll
  for (int i = 0; i < 16; i++)
    part[(unsigned)(s * 16 + i) * NPTS + (unsigned)g] = m[i];
}

// ============================ K2: merge 16 sorted 16-lists (coalesced) ========
__global__ __launch_bounds__(256) void k2_merge(const unsigned* __restrict__ part,
                                                int* __restrict__ knn_idx)
{
  const int g = blockIdx.x * 256 + threadIdx.x;
  unsigned run[16];
#pragma unroll
  for (int i = 0; i < 16; i++) run[i] = part[i * NPTS + g];
#pragma unroll
  for (int l = 1; l < SPL; l++) {
#pragma unroll
    for (int i = 0; i < 16; i++)
      run[i] = umn(run[i], part[(l * 16 + 15 - i) * NPTS + g]);
#pragma unroll
    for (int d = 8; d; d >>= 1) {
#pragma unroll
      for (int i = 0; i < 16; i++) {
        if ((i & d) == 0) {
          const int l2 = i | d;
          unsigned lo = umn(run[i], run[l2]);
          unsigned hi = umx(run[i], run[l2]);
          run[i] = lo; run[l2] = hi;
        }
      }
    }
  }
  const int base = (g >> 13) * NN;
  int outv[16];
#pragma unroll
  for (int i = 0; i < 16; i++) outv[i] = base + (int)(run[i] & 0x1FFFu);
  int4* o = (int4*)(knn_idx + g * 16);
  o[0] = make_int4(outv[0], outv[1], outv[2], outv[3]);
  o[1] = make_int4(outv[4], outv[5], outv[6], outv[7]);
  o[2] = make_int4(outv[8], outv[9], outv[10], outv[11]);
  o[3] = make_int4(outv[12], outv[13], outv[14], outv[15]);
}

// ============================ K34: fused emb+qkv; kv interleaved [p][128] =====
__global__ __launch_bounds__(256) void k34_embqkv(
    const float* __restrict__ feat, const float* __restrict__ wb,
    float* __restrict__ qo, float* __restrict__ kv)
{
  __shared__ float wl[16384];   // emb | q | k | v  (64 KB)
  __shared__ float xl[2048];    // 32 rows x 64     (8 KB)
  for (int i = threadIdx.x; i < 16384; i += 256) wl[i] = wb[W_EMB + i];
  const int col = threadIdx.x & 63;
  const int rg = threadIdx.x >> 6;
  const int row0 = blockIdx.x * 32 + rg * 8;
  const int rowu = __builtin_amdgcn_readfirstlane(row0);
  __syncthreads();
  {
    float acc[8];
    float bias = wb[B_EMB + col];
#pragma unroll
    for (int r = 0; r < 8; r++) acc[r] = bias;
    for (int c = 0; c < 64; c++) {
      float w = wl[c * 64 + col];
      const float* fp = feat + rowu * 64 + c;   // uniform -> scalar loads
#pragma unroll
      for (int r = 0; r < 8; r++) acc[r] = fmaf(fp[r * 64], w, acc[r]);
    }
#pragma unroll
    for (int r = 0; r < 8; r++) xl[(rg * 8 + r) * 64 + col] = acc[r];
  }
  __syncthreads();
  float aq[8], ak[8], av[8];
#pragma unroll
  for (int r = 0; r < 8; r++) { aq[r] = 0.f; ak[r] = 0.f; av[r] = 0.f; }
  for (int c = 0; c < 64; c++) {
    float w0 = wl[4096 + c * 64 + col];
    float w1 = wl[8192 + c * 64 + col];
    float w2 = wl[12288 + c * 64 + col];
#pragma unroll
    for (int r = 0; r < 8; r++) {
      float xv = xl[(rg * 8 + r) * 64 + c];
      aq[r] = fmaf(xv, w0, aq[r]);
      ak[r] = fmaf(xv, w1, ak[r]);
      av[r] = fmaf(xv, w2, av[r]);
    }
  }
#pragma unroll
  for (int r = 0; r < 8; r++) {
    qo[(row0 + r) * 64 + col] = aq[r];
    kv[(row0 + r) * 128 + col] = ak[r];
    kv[(row0 + r) * 128 + 64 + col] = av[r];
  }
}

// ============================ K5: MFMA fused posenc/attn/softmax/out ==========
// B-mats in LDS (pre-swizzled by k0 -> straight memcpy, cheap read offsets);
// no forced min-waves (R7 spill lesson); 34 KB LDS -> 4 blocks/CU.
__device__ inline void mv(const unsigned short* hm, const unsigned short* wm,
                          const float bias[4], int ln, int quad, int s0, int s1,
                          f32x4 acc[4])
{
  bf16x8 a0 = *(const bf16x8*)(hm + ln * 64 + s0);
  bf16x8 a1 = *(const bf16x8*)(hm + ln * 64 + s1);
#pragma unroll
  for (int t = 0; t < 4; t++) {
    const int fr = (t * 16 + ln) * 64;
    bf16x8 b0 = *(const bf16x8*)(wm + fr + s0);
    bf16x8 b1 = *(const bf16x8*)(wm + fr + s1);
    f32x4 a = {bias[t], bias[t], bias[t], bias[t]};
    a = __builtin_amdgcn_mfma_f32_16x16x32_bf16(a0, b0, a, 0, 0, 0);
    a = __builtin_amdgcn_mfma_f32_16x16x32_bf16(a1, b1, a, 0, 0, 0);
    acc[t] = a;
  }
}

__global__ __launch_bounds__(256) void k5_attn(
    const float* __restrict__ pos4, const float* __restrict__ qg,
    const float* __restrict__ kv, const float* __restrict__ featf,
    const float* __restrict__ wb, const unsigned short* __restrict__ wt,
    const int* __restrict__ knn, float* __restrict__ out)
{
  __shared__ unsigned short hma[4][1024];   // per-wave 16x64 bf16 h (8 KB)
  __shared__ unsigned short resm[1024];     // 16 points x 64 bf16   (2 KB)
  __shared__ unsigned short wtl[3 * 4096];  // pre-swizzled B-mats   (24 KB)
  const int tid = threadIdx.x;
  const int wid = tid >> 6, lane = tid & 63;
  const int ln = lane & 15, quad = lane >> 4;
  unsigned short* hm = hma[wid];
  const int s0 = ((quad + ln) & 7) << 3;        // fragment swizzle offsets
  const int s1 = ((4 + quad + ln) & 7) << 3;

  // straight coalesced copy (no swizzle math - k0 pre-swizzled)
  for (int i = tid; i < 1536; i += 256)
    ((uint4*)wtl)[i] = ((const uint4*)wt)[i];
  // epilogue fragments in regs (8 VGPRs), mat 3 is linear
  bf16x8 bo[2];
#pragma unroll
  for (int ks = 0; ks < 2; ks++)
    bo[ks] = *(const bf16x8*)(wt + 3 * 4096 + (wid * 16 + ln) * 64 +
                              ks * 32 + quad * 8);

  float pw10 = wb[W_PE1 + lane], pw11 = wb[W_PE1 + 64 + lane],
        pw12 = wb[W_PE1 + 128 + lane];
  float pb1 = wb[B_PE1 + lane];
  float bpe[4], ba1[4], ba2[4];
#pragma unroll
  for (int t = 0; t < 4; t++) {
    bpe[t] = wb[B_PE2 + t * 16 + ln];
    ba1[t] = wb[B_AT1 + t * 16 + ln];
    ba2[t] = wb[B_AT2 + t * 16 + ln];
  }
  __syncthreads();

  for (int pp = 0; pp < 4; pp++) {
    const int p = blockIdx.x * 16 + wid * 4 + pp;
    const int ps = __builtin_amdgcn_readfirstlane(p);
    const int4* ip4 = (const int4*)(knn + ps * 16);
    int jj[16];
#pragma unroll
    for (int u = 0; u < 4; u++) {
      int4 t4 = ip4[u];
      jj[u*4+0] = t4.x; jj[u*4+1] = t4.y; jj[u*4+2] = t4.z; jj[u*4+3] = t4.w;
    }
    const float* mp = pos4 + ps * 4;
    float pnx = mp[0], pny = mp[1], pnz = mp[2];
#pragma unroll
    for (int j = 0; j < 16; j++) {
      const float* np_ = pos4 + jj[j] * 4;
      float h1 = fmaf(np_[2] - pnz, pw12,
                 fmaf(np_[1] - pny, pw11,
                 fmaf(np_[0] - pnx, pw10, pb1)));
      hm[j * 64 + HCOL(lane, j)] = f2bf(fmaxf(h1, 0.f));
    }
    f32x4 accp[4];
    mv(hm, wtl, bpe, ln, quad, s0, s1, accp);          // posenc
    float vpe[4][4], qv[4];
#pragma unroll
    for (int t = 0; t < 4; t++) qv[t] = qg[p * 64 + t * 16 + ln];
#pragma unroll
    for (int r = 0; r < 4; r++) {
      const int j = quad * 4 + r;
      const float* kp = kv + jj[j] * 128 + ln;   // one base; k/v via imm offs
#pragma unroll
      for (int t = 0; t < 4; t++) {
        float pe = accp[t][r];
        float kf = kp[t * 16];
        float vf = kp[64 + t * 16];
        vpe[t][r] = vf + pe;
        hm[j * 64 + HCOL(t * 16 + ln, j)] = f2bf(qv[t] - kf + pe);
      }
    }
    f32x4 acch[4];
    mv(hm, wtl + 4096, ba1, ln, quad, s0, s1, acch);   // hh @ at_w1 + b
#pragma unroll
    for (int t = 0; t < 4; t++)
#pragma unroll
      for (int r = 0; r < 4; r++) {
        const int j = quad * 4 + r;
        hm[j * 64 + HCOL(t * 16 + ln, j)] = f2bf(fmaxf(acch[t][r], 0.f));
      }
    f32x4 lg[4];
    mv(hm, wtl + 8192, ba2, ln, quad, s0, s1, lg);     // logits
    const int pb = wid * 4 + pp;
#pragma unroll
    for (int t = 0; t < 4; t++) {
      float mx = fmaxf(fmaxf(lg[t][0], lg[t][1]), fmaxf(lg[t][2], lg[t][3]));
      mx = fmaxf(mx, __shfl_xor(mx, 16));
      mx = fmaxf(mx, __shfl_xor(mx, 32));
      float e0 = __expf((lg[t][0] - mx) * 0.125f);
      float e1 = __expf((lg[t][1] - mx) * 0.125f);
      float e2 = __expf((lg[t][2] - mx) * 0.125f);
      float e3 = __expf((lg[t][3] - mx) * 0.125f);
      float ss = (e0 + e1) + (e2 + e3);
      float dt = fmaf(e3, vpe[t][3], fmaf(e2, vpe[t][2],
                 fmaf(e1, vpe[t][1], e0 * vpe[t][0])));
      ss += __shfl_xor(ss, 16); ss += __shfl_xor(ss, 32);
      dt += __shfl_xor(dt, 16); dt += __shfl_xor(dt, 32);
      float res = dt / ss;
      if (quad == 0) resm[pb * 64 + HCOL(t * 16 + ln, pb)] = f2bf(res);
    }
  }
  __syncthreads();
  // epilogue: 16 points = 1 M-tile x 4 N-tiles; wave wid handles N-tile wid
  {
    const int nt = wid;
    float ob = wb[B_OUT + nt * 16 + ln];
    f32x4 acc = {ob, ob, ob, ob};
#pragma unroll
    for (int ks = 0; ks < 2; ks++) {
      bf16x8 a = *(const bf16x8*)(resm + ln * 64 +
                                  (((ks * 4 + quad + ln) & 7) << 3));
      acc = __builtin_amdgcn_mfma_f32_16x16x32_bf16(a, bo[ks], acc, 0, 0, 0);
    }
#pragma unroll
    for (int r = 0; r < 4; r++) {
      const int pt = blockIdx.x * 16 + quad * 4 + r;
      const int f = nt * 16 + ln;
      out[pt * 64 + f] = acc[r] + featf[pt * 64 + f];
    }
  }
}

// ============================ launcher ========================================
extern "C" void kernel_launch(void* const* d_in, const int* in_sizes, int n_in,
                              void* d_out, int out_size, void* d_ws, size_t ws_size,
                              hipStream_t stream)
{
  (void)in_sizes; (void)n_in; (void)out_size; (void)ws_size;
  const float* pos   = (const float*)d_in[0];
  const float* feat  = (const float*)d_in[1];
  const float* emb_w = (const float*)d_in[2];
  const float* emb_b = (const float*)d_in[3];
  const float* wq    = (const float*)d_in[4];
  const float* wk    = (const float*)d_in[5];
  const float* wv    = (const float*)d_in[6];
  const float* pe_w1 = (const float*)d_in[7];
  const float* pe_b1 = (const float*)d_in[8];
  const float* pe_w2 = (const float*)d_in[9];
  const float* pe_b2 = (const float*)d_in[10];
  const float* at_w1 = (const float*)d_in[11];
  const float* at_b1 = (const float*)d_in[12];
  const float* at_w2 = (const float*)d_in[13];
  const float* at_b2 = (const float*)d_in[14];
  const float* out_w = (const float*)d_in[15];
  const float* out_b = (const float*)d_in[16];
  float* ws = (float*)d_ws;

  k0_stage<<<259, 256, 0, stream>>>(pos, emb_w, emb_b, wq, wk, wv,
      pe_w1, pe_b1, pe_w2, pe_b2, at_w1, at_b1, at_w2, at_b2, out_w, out_b, ws);
  dim3 g1(NPTS / 256, SPL);
  k1_knn<<<g1, 256, 0, stream>>>(ws + POS4_OFF, (unsigned*)ws + PART_OFF);
  k2_merge<<<NPTS / 256, 256, 0, stream>>>((unsigned*)ws + PART_OFF,
                                           (int*)ws + IDX_OFF);
  k34_embqkv<<<NPTS / 32, 256, 0, stream>>>(feat, ws + WBUF_OFF,
                                            ws + QB_OFF, ws + KVB_OFF);
  k5_attn<<<NPTS / 16, 256, 0, stream>>>(ws + POS4_OFF, ws + QB_OFF,
      ws + KVB_OFF, feat, ws + WBUF_OFF, (unsigned short*)(ws + WT_OFF),
      (int*)ws + IDX_OFF, (float*)d_out);
}

// Round 9
// 236.871 us; speedup vs baseline: 1.3173x; 1.1348x over previous
//
#include <hip/hip_runtime.h>
#include <hip/hip_bf16.h>

#define BB 2
#define NN 8192
#define SPL 16
#define CAND (NN/SPL)
#define NPTS (BB*NN)

// ---- workspace layout (units: 4-byte words) ----
#define POS4_OFF 0u
#define WBUF_OFF 65536u
#define PART_OFF 99328u                 /* 256*NPTS words; dead after k2 */
#define QB_OFF   99328u                 /* overlays PART (born at k34) */
#define KVB_OFF  (QB_OFF + 1048576u)    /* packed bf16 kv: 1 uint per (p,c) */
#define IDX_OFF  4293632u               /* after PART */
#define WT_OFF   (IDX_OFF + 262144u)    /* 4 mats x 4096 bf16 = 8192 words */

// ---- wbuf internal offsets (words) ----
#define W_EMB 0
#define W_Q   4096
#define W_K   8192
#define W_V   12288
#define W_PE2 16384
#define W_AT1 20480
#define W_AT2 24576
#define W_OUT 28672
#define W_PE1 32768
#define B_EMB 32960
#define B_PE1 33024
#define B_PE2 33088
#define B_AT1 33152
#define B_AT2 33216
#define B_OUT 33280

typedef __attribute__((ext_vector_type(8))) short bf16x8;
typedef __attribute__((ext_vector_type(4))) float f32x4;

__device__ __forceinline__ unsigned umn(unsigned a, unsigned b) {
#if __has_builtin(__builtin_elementwise_min)
  return __builtin_elementwise_min(a, b);
#else
  return a < b ? a : b;
#endif
}
__device__ __forceinline__ unsigned umx(unsigned a, unsigned b) {
#if __has_builtin(__builtin_elementwise_max)
  return __builtin_elementwise_max(a, b);
#else
  return a < b ? b : a;
#endif
}

__device__ inline unsigned short f2bf(float x) {
  __hip_bfloat16 b = __float2bfloat16(x);
  return *(unsigned short*)&b;
}

// column-block rotate swizzle for conflict-free ds_read_b128 fragments
#define HCOL(c, j) ((((((c) >> 3) + (j)) & 7) << 3) | ((c) & 7))

// ============================ K0: stage pos4(+|c|^2), weights, bf16-T mats ====
__global__ __launch_bounds__(256) void k0_stage(
    const float* __restrict__ pos,
    const float* __restrict__ emb_w, const float* __restrict__ emb_b,
    const float* __restrict__ wq, const float* __restrict__ wk,
    const float* __restrict__ wv,
    const float* __restrict__ pe_w1, const float* __restrict__ pe_b1,
    const float* __restrict__ pe_w2, const float* __restrict__ pe_b2,
    const float* __restrict__ at_w1, const float* __restrict__ at_b1,
    const float* __restrict__ at_w2, const float* __restrict__ at_b2,
    const float* __restrict__ out_w, const float* __restrict__ out_b,
    float* __restrict__ ws)
{
  int t = blockIdx.x * 256 + threadIdx.x;
  if (t < NPTS) {
    float x = pos[t * 3 + 0], y = pos[t * 3 + 1], z = pos[t * 3 + 2];
    float* o = ws + POS4_OFF + t * 4;
    o[0] = x; o[1] = y; o[2] = z;
    o[3] = fmaf(x, x, fmaf(y, y, z * z));
    return;
  }
  t -= NPTS;
  float* wbuf = ws + WBUF_OFF;
  if (t < 32768) {
    const float* s;
    switch (t >> 12) {
      case 0: s = emb_w; break;
      case 1: s = wq;    break;
      case 2: s = wk;    break;
      case 3: s = wv;    break;
      case 4: s = pe_w2; break;
      case 5: s = at_w1; break;
      case 6: s = at_w2; break;
      default: s = out_w; break;
    }
    wbuf[t] = s[t & 4095];
    return;
  }
  t -= 32768;
  if (t < 192) { wbuf[W_PE1 + t] = pe_w1[t]; return; }
  t -= 192;
  if (t < 384) {
    const float* s;
    switch (t >> 6) {
      case 0: s = emb_b; break;
      case 1: s = pe_b1; break;
      case 2: s = pe_b2; break;
      case 3: s = at_b1; break;
      case 4: s = at_b2; break;
      default: s = out_b; break;
    }
    wbuf[B_EMB + t] = s[t & 63];
    return;
  }
  t -= 384;
  if (t < 16384) {  // bf16 transposed mats: wt[m][f*64+c] = W_m[c*64+f]
    unsigned short* wt = (unsigned short*)(ws + WT_OFF);
    const float* s;
    switch (t >> 12) {
      case 0: s = pe_w2; break;
      case 1: s = at_w1; break;
      case 2: s = at_w2; break;
      default: s = out_w; break;
    }
    int idx = t & 4095, f = idx >> 6, c = idx & 63;
    wt[t] = f2bf(s[c * 64 + f]);
  }
}

// ============================ K1: KNN, batch-16 OEMS selection ================
__global__ __launch_bounds__(256) void k1_knn(const float* __restrict__ pos4,
                                              unsigned* __restrict__ part)
{
  const int tid = threadIdx.x;
  const int g = blockIdx.x * 256 + tid;
  const int s = blockIdx.y;
  const int bu = __builtin_amdgcn_readfirstlane(g >> 13);
  const float4* __restrict__ allp = (const float4*)pos4;
  const float4 q = allp[g];
  const float qx2 = -2.f * q.x, qy2 = -2.f * q.y, qz2 = -2.f * q.z;
  const float sqq = q.w + 1e-5f;     // bias keeps d2>0 under rounding: no fmax
  const float4* __restrict__ cand = allp + (bu * NN + s * CAND);
  unsigned m[16];
#pragma unroll
  for (int i = 0; i < 16; i++) m[i] = 0xFFFFFFFFu;
  const unsigned jb = (unsigned)(s * CAND);

  constexpr int OE[63][2] = {
    {0,1},{2,3},{4,5},{6,7},{8,9},{10,11},{12,13},{14,15},
    {0,2},{1,3},{4,6},{5,7},{8,10},{9,11},{12,14},{13,15},
    {1,2},{5,6},{9,10},{13,14},
    {0,4},{1,5},{2,6},{3,7},{8,12},{9,13},{10,14},{11,15},
    {2,4},{3,5},{10,12},{11,13},
    {1,2},{3,4},{5,6},{9,10},{11,12},{13,14},
    {0,8},{1,9},{2,10},{3,11},{4,12},{5,13},{6,14},{7,15},
    {4,8},{5,9},{6,10},{7,11},
    {2,4},{3,5},{6,8},{7,9},{10,12},{11,13},
    {1,2},{3,4},{5,6},{7,8},{9,10},{11,12},{13,14}
  };

  for (int j0 = 0; j0 < CAND; j0 += 16) {
    unsigned b[16];
#pragma unroll
    for (int i = 0; i < 16; i++) {
      float4 cp = cand[j0 + i];                // wave-uniform -> scalar loads
      float d2 = fmaf(cp.x, qx2, fmaf(cp.y, qy2, fmaf(cp.z, qz2, cp.w + sqq)));
      b[i] = (__float_as_uint(d2) & 0xFFFFE000u) | (jb + (unsigned)(j0 + i));
    }
#pragma unroll
    for (int c = 0; c < 63; c++) {
      const int x = OE[c][0], y = OE[c][1];
      unsigned lo = umn(b[x], b[y]);
      unsigned hi = umx(b[x], b[y]);
      b[x] = hi; b[y] = lo;
    }
#pragma unroll
    for (int i = 0; i < 16; i++) m[i] = umn(m[i], b[i]);
#pragma unroll
    for (int d = 8; d; d >>= 1) {
#pragma unroll
      for (int i = 0; i < 16; i++) {
        if ((i & d) == 0) {
          const int l = i | d;
          unsigned lo = umn(m[i], m[l]);
          unsigned hi = umx(m[i], m[l]);
          m[i] = lo; m[l] = hi;
        }
      }
    }
  }
#pragma unroll
  for (int i = 0; i < 16; i++)
    part[(unsigned)(s * 16 + i) * NPTS + (unsigned)g] = m[i];
}

// ============================ K2: merge 16 sorted 16-lists (coalesced) ========
__global__ __launch_bounds__(256) void k2_merge(const unsigned* __restrict__ part,
                                                int* __restrict__ knn_idx)
{
  const int g = blockIdx.x * 256 + threadIdx.x;
  unsigned run[16];
#pragma unroll
  for (int i = 0; i < 16; i++) run[i] = part[i * NPTS + g];
#pragma unroll
  for (int l = 1; l < SPL; l++) {
#pragma unroll
    for (int i = 0; i < 16; i++)
      run[i] = umn(run[i], part[(l * 16 + 15 - i) * NPTS + g]);
#pragma unroll
    for (int d = 8; d; d >>= 1) {
#pragma unroll
      for (int i = 0; i < 16; i++) {
        if ((i & d) == 0) {
          const int l2 = i | d;
          unsigned lo = umn(run[i], run[l2]);
          unsigned hi = umx(run[i], run[l2]);
          run[i] = lo; run[l2] = hi;
        }
      }
    }
  }
  const int base = (g >> 13) * NN;
  int outv[16];
#pragma unroll
  for (int i = 0; i < 16; i++) outv[i] = base + (int)(run[i] & 0x1FFFu);
  int4* o = (int4*)(knn_idx + g * 16);
  o[0] = make_int4(outv[0], outv[1], outv[2], outv[3]);
  o[1] = make_int4(outv[4], outv[5], outv[6], outv[7]);
  o[2] = make_int4(outv[8], outv[9], outv[10], outv[11]);
  o[3] = make_int4(outv[12], outv[13], outv[14], outv[15]);
}

// ============================ K34: fused emb+qkv; kv packed bf16 pairs ========
__global__ __launch_bounds__(256) void k34_embqkv(
    const float* __restrict__ feat, const float* __restrict__ wb,
    float* __restrict__ qo, unsigned* __restrict__ kvp)
{
  __shared__ float wl[16384];   // emb | q | k | v  (64 KB)
  __shared__ float xl[2048];    // 32 rows x 64     (8 KB)
  for (int i = threadIdx.x; i < 16384; i += 256) wl[i] = wb[W_EMB + i];
  const int col = threadIdx.x & 63;
  const int rg = threadIdx.x >> 6;
  const int row0 = blockIdx.x * 32 + rg * 8;
  const int rowu = __builtin_amdgcn_readfirstlane(row0);
  __syncthreads();
  {
    float acc[8];
    float bias = wb[B_EMB + col];
#pragma unroll
    for (int r = 0; r < 8; r++) acc[r] = bias;
    for (int c = 0; c < 64; c++) {
      float w = wl[c * 64 + col];
      const float* fp = feat + rowu * 64 + c;   // uniform -> scalar loads
#pragma unroll
      for (int r = 0; r < 8; r++) acc[r] = fmaf(fp[r * 64], w, acc[r]);
    }
#pragma unroll
    for (int r = 0; r < 8; r++) xl[(rg * 8 + r) * 64 + col] = acc[r];
  }
  __syncthreads();
  float aq[8], ak[8], av[8];
#pragma unroll
  for (int r = 0; r < 8; r++) { aq[r] = 0.f; ak[r] = 0.f; av[r] = 0.f; }
  for (int c = 0; c < 64; c++) {
    float w0 = wl[4096 + c * 64 + col];
    float w1 = wl[8192 + c * 64 + col];
    float w2 = wl[12288 + c * 64 + col];
#pragma unroll
    for (int r = 0; r < 8; r++) {
      float xv = xl[(rg * 8 + r) * 64 + c];
      aq[r] = fmaf(xv, w0, aq[r]);
      ak[r] = fmaf(xv, w1, ak[r]);
      av[r] = fmaf(xv, w2, av[r]);
    }
  }
#pragma unroll
  for (int r = 0; r < 8; r++) {
    qo[(row0 + r) * 64 + col] = aq[r];
    kvp[(row0 + r) * 64 + col] =
        ((unsigned)f2bf(av[r]) << 16) | (unsigned)f2bf(ak[r]);
  }
}

// ============================ K5: MFMA fused posenc/attn/softmax/out ==========
// Bf in registers (R6 structure); launch_bounds(256,2) caps unified regs at
// 256 (2 waves/SIMD) without R7-style spills; next-point idx prefetch + kv/q
// gathers issued BEFORE mv1 so their latency hides under the posenc chain.
__device__ inline void mv(const unsigned short* hm, const bf16x8 B[4][2],
                          const float bias[4], int ln, int s0, int s1,
                          f32x4 acc[4])
{
  bf16x8 a0 = *(const bf16x8*)(hm + ln * 64 + s0);
  bf16x8 a1 = *(const bf16x8*)(hm + ln * 64 + s1);
#pragma unroll
  for (int t = 0; t < 4; t++) {
    f32x4 a = {bias[t], bias[t], bias[t], bias[t]};
    a = __builtin_amdgcn_mfma_f32_16x16x32_bf16(a0, B[t][0], a, 0, 0, 0);
    a = __builtin_amdgcn_mfma_f32_16x16x32_bf16(a1, B[t][1], a, 0, 0, 0);
    acc[t] = a;
  }
}

__global__ __launch_bounds__(256, 2) void k5_attn(
    const float* __restrict__ pos4, const float* __restrict__ qg,
    const unsigned* __restrict__ kvp, const float* __restrict__ featf,
    const float* __restrict__ wb, const unsigned short* __restrict__ wt,
    const int* __restrict__ knn, float* __restrict__ out)
{
  __shared__ unsigned short hma[4][1024];   // per-wave 16x64 bf16 h (8 KB)
  __shared__ unsigned short resm[1024];     // 16 points x 64 bf16   (2 KB)
  const int tid = threadIdx.x;
  const int wid = tid >> 6, lane = tid & 63;
  const int ln = lane & 15, quad = lane >> 4;
  unsigned short* hm = hma[wid];
  const int s0 = ((quad + ln) & 7) << 3;        // fragment swizzle offsets
  const int s1 = ((4 + quad + ln) & 7) << 3;

  bf16x8 Bf[3][4][2];                       // pe_w2^T | at_w1^T | at_w2^T frags
#pragma unroll
  for (int m = 0; m < 3; m++)
#pragma unroll
    for (int t = 0; t < 4; t++)
#pragma unroll
      for (int ks = 0; ks < 2; ks++)
        Bf[m][t][ks] = *(const bf16x8*)(wt + m * 4096 + (t * 16 + ln) * 64 +
                                        ks * 32 + quad * 8);
  bf16x8 bo[2];                             // epilogue frags (N-tile = wid)
#pragma unroll
  for (int ks = 0; ks < 2; ks++)
    bo[ks] = *(const bf16x8*)(wt + 3 * 4096 + (wid * 16 + ln) * 64 +
                              ks * 32 + quad * 8);

  float pw10 = wb[W_PE1 + lane], pw11 = wb[W_PE1 + 64 + lane],
        pw12 = wb[W_PE1 + 128 + lane];
  float pb1 = wb[B_PE1 + lane];
  float bpe[4], ba1[4], ba2[4];
#pragma unroll
  for (int t = 0; t < 4; t++) {
    bpe[t] = wb[B_PE2 + t * 16 + ln];
    ba1[t] = wb[B_AT1 + t * 16 + ln];
    ba2[t] = wb[B_AT2 + t * 16 + ln];
  }

  const int p0 = blockIdx.x * 16 + wid * 4;
  const int ps0 = __builtin_amdgcn_readfirstlane(p0);
  int4 cur[4];
  {
    const int4* ip4 = (const int4*)(knn + ps0 * 16);
#pragma unroll
    for (int u = 0; u < 4; u++) cur[u] = ip4[u];
  }

  for (int pp = 0; pp < 4; pp++) {
    const int p = p0 + pp;
    const int ps = __builtin_amdgcn_readfirstlane(p);
    int jj[16];
#pragma unroll
    for (int u = 0; u < 4; u++) {
      jj[u*4+0] = cur[u].x; jj[u*4+1] = cur[u].y;
      jj[u*4+2] = cur[u].z; jj[u*4+3] = cur[u].w;
    }
    // prefetch next point's indices (in flight through this whole point)
    int4 nxt[4];
    {
      const int pn = (pp < 3) ? (ps + 1) : ps;
      const int4* np4 = (const int4*)(knn + pn * 16);
#pragma unroll
      for (int u = 0; u < 4; u++) nxt[u] = np4[u];
    }
    // issue kv + q gathers EARLY: consumed only after mv1
    unsigned kvw[4][4];
#pragma unroll
    for (int r = 0; r < 4; r++) {
      const unsigned* kp = kvp + jj[quad * 4 + r] * 64 + ln;
#pragma unroll
      for (int t = 0; t < 4; t++) kvw[r][t] = kp[t * 16];
    }
    float qv[4];
#pragma unroll
    for (int t = 0; t < 4; t++) qv[t] = qg[p * 64 + t * 16 + ln];

    // posenc hidden: h1 = relu(gpos @ pe_w1 + pe_b1)
    const float* mp = pos4 + ps * 4;
    float pnx = mp[0], pny = mp[1], pnz = mp[2];
#pragma unroll
    for (int j = 0; j < 16; j++) {
      const float* np_ = pos4 + jj[j] * 4;
      float h1 = fmaf(np_[2] - pnz, pw12,
                 fmaf(np_[1] - pny, pw11,
                 fmaf(np_[0] - pnx, pw10, pb1)));
      hm[j * 64 + HCOL(lane, j)] = f2bf(fmaxf(h1, 0.f));
    }
    f32x4 accp[4];
    mv(hm, Bf[0], bpe, ln, s0, s1, accp);          // posenc (kv loads in flight)
    // hh = q - k + pe ; vpe = v + pe   (k,v unpacked from bf16 pair)
    float vpe[4][4];
#pragma unroll
    for (int r = 0; r < 4; r++) {
      const int j = quad * 4 + r;
#pragma unroll
      for (int t = 0; t < 4; t++) {
        const unsigned w = kvw[r][t];
        float kf = __uint_as_float(w << 16);
        float vf = __uint_as_float(w & 0xFFFF0000u);
        float pe = accp[t][r];
        vpe[t][r] = vf + pe;
        hm[j * 64 + HCOL(t * 16 + ln, j)] = f2bf(qv[t] - kf + pe);
      }
    }
    f32x4 acch[4];
    mv(hm, Bf[1], ba1, ln, s0, s1, acch);          // hh @ at_w1 + b
#pragma unroll
    for (int t = 0; t < 4; t++)
#pragma unroll
      for (int r = 0; r < 4; r++) {
        const int j = quad * 4 + r;
        hm[j * 64 + HCOL(t * 16 + ln, j)] = f2bf(fmaxf(acch[t][r], 0.f));
      }
    f32x4 lg[4];
    mv(hm, Bf[2], ba2, ln, s0, s1, lg);            // logits
    // per-channel softmax over 16 neighbors; logits tiny -> no max-sub needed
    const int pb = wid * 4 + pp;
#pragma unroll
    for (int t = 0; t < 4; t++) {
      float e0 = __expf(lg[t][0] * 0.125f);
      float e1 = __expf(lg[t][1] * 0.125f);
      float e2 = __expf(lg[t][2] * 0.125f);
      float e3 = __expf(lg[t][3] * 0.125f);
      float ss = (e0 + e1) + (e2 + e3);
      float dt = fmaf(e3, vpe[t][3], fmaf(e2, vpe[t][2],
                 fmaf(e1, vpe[t][1], e0 * vpe[t][0])));
      ss += __shfl_xor(ss, 16); ss += __shfl_xor(ss, 32);
      dt += __shfl_xor(dt, 16); dt += __shfl_xor(dt, 32);
      float res = dt / ss;
      if (quad == 0) resm[pb * 64 + HCOL(t * 16 + ln, pb)] = f2bf(res);
    }
#pragma unroll
    for (int u = 0; u < 4; u++) cur[u] = nxt[u];
  }
  __syncthreads();
  // epilogue: 16 points = 1 M-tile x 4 N-tiles; wave wid handles N-tile wid
  {
    const int nt = wid;
    float ob = wb[B_OUT + nt * 16 + ln];
    f32x4 acc = {ob, ob, ob, ob};
#pragma unroll
    for (int ks = 0; ks < 2; ks++) {
      bf16x8 a = *(const bf16x8*)(resm + ln * 64 +
                                  (((ks * 4 + quad + ln) & 7) << 3));
      acc = __builtin_amdgcn_mfma_f32_16x16x32_bf16(a, bo[ks], acc, 0, 0, 0);
    }
#pragma unroll
    for (int r = 0; r < 4; r++) {
      const int pt = blockIdx.x * 16 + quad * 4 + r;
      const int f = nt * 16 + ln;
      out[pt * 64 + f] = acc[r] + featf[pt * 64 + f];
    }
  }
}

// ============================ launcher ========================================
extern "C" void kernel_launch(void* const* d_in, const int* in_sizes, int n_in,
                              void* d_out, int out_size, void* d_ws, size_t ws_size,
                              hipStream_t stream)
{
  (void)in_sizes; (void)n_in; (void)out_size; (void)ws_size;
  const float* pos   = (const float*)d_in[0];
  const float* feat  = (const float*)d_in[1];
  const float* emb_w = (const float*)d_in[2];
  const float* emb_b = (const float*)d_in[3];
  const float* wq    = (const float*)d_in[4];
  const float* wk    = (const float*)d_in[5];
  const float* wv    = (const float*)d_in[6];
  const float* pe_w1 = (const float*)d_in[7];
  const float* pe_b1 = (const float*)d_in[8];
  const float* pe_w2 = (const float*)d_in[9];
  const float* pe_b2 = (const float*)d_in[10];
  const float* at_w1 = (const float*)d_in[11];
  const float* at_b1 = (const float*)d_in[12];
  const float* at_w2 = (const float*)d_in[13];
  const float* at_b2 = (const float*)d_in[14];
  const float* out_w = (const float*)d_in[15];
  const float* out_b = (const float*)d_in[16];
  float* ws = (float*)d_ws;

  k0_stage<<<259, 256, 0, stream>>>(pos, emb_w, emb_b, wq, wk, wv,
      pe_w1, pe_b1, pe_w2, pe_b2, at_w1, at_b1, at_w2, at_b2, out_w, out_b, ws);
  dim3 g1(NPTS / 256, SPL);
  k1_knn<<<g1, 256, 0, stream>>>(ws + POS4_OFF, (unsigned*)ws + PART_OFF);
  k2_merge<<<NPTS / 256, 256, 0, stream>>>((unsigned*)ws + PART_OFF,
                                           (int*)ws + IDX_OFF);
  k34_embqkv<<<NPTS / 32, 256, 0, stream>>>(feat, ws + WBUF_OFF,
                                            ws + QB_OFF, (unsigned*)ws + KVB_OFF);
  k5_attn<<<NPTS / 16, 256, 0, stream>>>(ws + POS4_OFF, ws + QB_OFF,
      (unsigned*)ws + KVB_OFF, feat, ws + WBUF_OFF,
      (unsigned short*)(ws + WT_OFF), (int*)ws + IDX_OFF, (float*)d_out);
}